// Round 2
// baseline (185.429 us; speedup 1.0000x reference)
//
#include <hip/hip_runtime.h>

typedef unsigned short u16;
typedef unsigned int u32;
typedef __bf16 bf16x8 __attribute__((ext_vector_type(8)));
typedef float f32x16 __attribute__((ext_vector_type(16)));

#define C2 (-7.213475204444817f) /* -5/ln(2): exp(-5 t^2) = exp2(C2 t^2) */

__device__ __forceinline__ u16 f2bf(float f) {
  u32 u = __float_as_uint(f);
  return (u16)((u + 0x7FFFu + ((u >> 16) & 1u)) >> 16);  // RNE
}

__device__ __forceinline__ void async16(const void* g, void* l) {
  __builtin_amdgcn_global_load_lds(
      (const __attribute__((address_space(1))) u32*)g,
      (__attribute__((address_space(3))) u32*)l, 16, 0, 0);
}

__device__ __forceinline__ f32x16 mfma16(uint4 a, uint4 b, f32x16 c) {
  return __builtin_amdgcn_mfma_f32_32x32x16_bf16(
      __builtin_bit_cast(bf16x8, a), __builtin_bit_cast(bf16x8, b), c, 0, 0, 0);
}

// ---------------------------------------------------------------------------
// Prep: f32 weights -> bf16, transposed. wst[s][u][d]:
//   s=0..4 -> spline_weight[d][u][s]; s=5 -> base_weight[d][u].
// grid (16,4): d-tiles of 64, u-tiles of 32; 256 threads.
// ---------------------------------------------------------------------------
__global__ __launch_bounds__(256) void kan_prep(const float* __restrict__ wb,
                                                const float* __restrict__ ws,
                                                u16* __restrict__ wst) {
  __shared__ __align__(16) u16 tile[6][32][72];  // pad 64->72: no pow2 stride
  const int t = threadIdx.x;
  const int d0 = blockIdx.x * 64;
  const int u0 = blockIdx.y * 32;
#pragma unroll
  for (int it = 0; it < 8; ++it) {
    int e = it * 256 + t;
    int uu = e & 31, dd = e >> 5;
    const float* p = ws + ((size_t)(d0 + dd) * 128 + (u0 + uu)) * 8;  // K=8 f32
    float4 v0 = *(const float4*)p;  // g = 0..3
    float g4 = p[4];                // g = 4
    tile[0][uu][dd] = f2bf(v0.x);
    tile[1][uu][dd] = f2bf(v0.y);
    tile[2][uu][dd] = f2bf(v0.z);
    tile[3][uu][dd] = f2bf(v0.w);
    tile[4][uu][dd] = f2bf(g4);
    tile[5][uu][dd] = f2bf(wb[(size_t)(d0 + dd) * 128 + (u0 + uu)]);
  }
  __syncthreads();
#pragma unroll
  for (int it = 0; it < 6; ++it) {
    int v = it * 256 + t;       // over 6*32*8 = 1536 16B-vectors
    int s = v >> 8;             // /(32*8)
    int r = v & 255;
    int uu = r >> 3, dseg = r & 7;
    uint4 val = *(const uint4*)&tile[s][uu][dseg * 8];
    *(uint4*)(wst + (size_t)(s * 128 + u0 + uu) * 1024 + d0 + dseg * 8) = val;
  }
}

// ---------------------------------------------------------------------------
// Main fused kernel. Block tile 64m x 128n, 4 waves 2x2 -> wave 32m x 64n.
// Subs: 0..4 = rbf_g (computed on-chip from f32 x), 5 = bf16(x) (base path).
// mfma_f32_32x32x16_bf16: A[m=lane&31][k=(lane>>5)*8+j], B[n=lane&31][k=...],
// C/D: col=lane&31, row=(reg&3)+8*(reg>>2)+4*(lane>>5)   [m74/m101-verified]
// ---------------------------------------------------------------------------
__global__ __launch_bounds__(256, 2) void kan_main(const float* __restrict__ x,
                                                   const u16* __restrict__ wst,
                                                   float* __restrict__ out) {
  __shared__ __align__(16) u16 As[6][64][32];    // 24 KB
  __shared__ __align__(16) u16 Bs[6][128][32];   // 48 KB

  const int t = threadIdx.x;
  const int lane = t & 63;
  const int w = t >> 6;
  const int wm = w >> 1;   // m-group 0..1
  const int wn = w & 1;    // n-group 0..1
  const int b0 = blockIdx.x * 64;

  f32x16 accb[2], accs[2];
#pragma unroll
  for (int i = 0; i < 16; ++i) {
    accb[0][i] = 0.f; accb[1][i] = 0.f;
    accs[0][i] = 0.f; accs[1][i] = 0.f;
  }

  u16* Asf = &As[0][0][0];
  u16* Bsf = &Bs[0][0][0];

  // thread t owns x row t>>2, 8-elem segment t&3 (LDS dest = t*16 B: the
  // wave-uniform-base + lane*16 pattern the DMA-style layout needs, and the
  // same slot this thread's rbf values go to)
  const int xrow = t >> 2, xseg = t & 3;
  const float* xbase = x + (size_t)(b0 + xrow) * 1024 + xseg * 8;

  const int arow = wm * 32 + (lane & 31);
  const int kc = (lane >> 5) * 8;

  for (int k0 = 0; k0 < 1024; k0 += 32) {
    // ---- stage weights -> Bs (48 KB, 12 async DMAs/thread; in flight
    //      while we compute rbf below)
#pragma unroll
    for (int i = 0; i < 12; ++i) {
      int e = i * 256 + t;   // 16B-vec index; LDS dest byte = e*16 (uniform+lane*16)
      int s = e >> 9;        // 512 vecs per sub (128 rows x 4 segs)
      int r = e & 511;
      int u = r >> 2, seg = r & 3;
      async16(wst + (s * 128 + u) * 1024 + k0 + seg * 8, Bsf + e * 8);
    }

    // ---- load 8 f32 x values, compute bf16(x) + 5 rbf_g, write LDS
    float4 xa = *(const float4*)(xbase + k0);
    float4 xb = *(const float4*)(xbase + k0 + 4);
    float xf[8] = {xa.x, xa.y, xa.z, xa.w, xb.x, xb.y, xb.z, xb.w};

    uint4 xo;
    xo.x = (u32)f2bf(xf[0]) | ((u32)f2bf(xf[1]) << 16);
    xo.y = (u32)f2bf(xf[2]) | ((u32)f2bf(xf[3]) << 16);
    xo.z = (u32)f2bf(xf[4]) | ((u32)f2bf(xf[5]) << 16);
    xo.w = (u32)f2bf(xf[6]) | ((u32)f2bf(xf[7]) << 16);
    *((uint4*)(Asf + 5 * 2048) + t) = xo;

#pragma unroll
    for (int g = 0; g < 5; ++g) {
      float cg = -1.0f + 0.5f * (float)g;
      u32 rr[4];
#pragma unroll
      for (int q = 0; q < 4; ++q) {
        float t0 = xf[2 * q] - cg;
        float t1 = xf[2 * q + 1] - cg;
        float e0 = __builtin_amdgcn_exp2f(C2 * t0 * t0);  // raw v_exp_f32
        float e1 = __builtin_amdgcn_exp2f(C2 * t1 * t1);
        rr[q] = (u32)f2bf(e0) | ((u32)f2bf(e1) << 16);
      }
      uint4 o; o.x = rr[0]; o.y = rr[1]; o.z = rr[2]; o.w = rr[3];
      *((uint4*)(Asf + g * 2048) + t) = o;
    }
    __syncthreads();  // drains DMA (vmcnt0) + rbf ds_writes before MFMA reads

    // ---- MFMA: 2 k-steps x 6 subs x 2 n-tiles = 24 mfma / wave / chunk
#pragma unroll
    for (int kk = 0; kk < 2; ++kk) {
#pragma unroll
      for (int s = 0; s < 6; ++s) {
        uint4 a = *(const uint4*)(Asf + (s * 64 + arow) * 32 + kk * 16 + kc);
#pragma unroll
        for (int nt = 0; nt < 2; ++nt) {
          uint4 bv = *(const uint4*)(Bsf + (s * 128 + wn * 64 + nt * 32 + (lane & 31)) * 32 +
                                     kk * 16 + kc);
          if (s < 5) accs[nt] = mfma16(a, bv, accs[nt]);
          else       accb[nt] = mfma16(a, bv, accb[nt]);
        }
      }
    }
    __syncthreads();  // protect LDS before next chunk's DMA/stores
  }

  // ---- epilogue: silu(base) + spline, store f32
  const int col = lane & 31;
#pragma unroll
  for (int nt = 0; nt < 2; ++nt) {
#pragma unroll
    for (int reg = 0; reg < 16; ++reg) {
      int row = (reg & 3) + 8 * (reg >> 2) + 4 * (lane >> 5);
      int m = wm * 32 + row;
      int n = wn * 64 + nt * 32 + col;
      float z = accb[nt][reg];
      float sv = z / (1.0f + __expf(-z));  // silu
      out[(size_t)(b0 + m) * 128 + n] = sv + accs[nt][reg];
    }
  }
}

extern "C" void kernel_launch(void* const* d_in, const int* in_sizes, int n_in,
                              void* d_out, int out_size, void* d_ws, size_t ws_size,
                              hipStream_t stream) {
  const float* x  = (const float*)d_in[0];   // [16384][1024] f32
  const float* wb = (const float*)d_in[1];   // [1024][128]   f32
  const float* ws = (const float*)d_in[2];   // [1024][128][8] f32
  u16* wst = (u16*)d_ws;                     // [6][128][1024] bf16 = 1.5 MB
  float* out = (float*)d_out;                // [16384][128]  f32

  kan_prep<<<dim3(16, 4), 256, 0, stream>>>(wb, ws, wst);
  kan_main<<<dim3(256), 256, 0, stream>>>(x, wst, out);
}

// Round 3
// 147.073 us; speedup vs baseline: 1.2608x; 1.2608x over previous
//
#include <hip/hip_runtime.h>

typedef unsigned short u16;
typedef unsigned int u32;
typedef __bf16 bf16x8 __attribute__((ext_vector_type(8)));
typedef float f32x16 __attribute__((ext_vector_type(16)));

#define C2 (-7.213475204444817f) /* -5/ln2 : exp(-5 t^2) = exp2(C2 t^2) */
#define T1C 0.28650480f          /* e^-1.25 */
#define T2C 0.0067379470f        /* e^-5    */

__device__ __forceinline__ u16 f2bf(float f) {
  u32 u = __float_as_uint(f);
  return (u16)((u + 0x7FFFu + ((u >> 16) & 1u)) >> 16);  // RNE
}

__device__ __forceinline__ void async16(const void* g, void* l) {
  __builtin_amdgcn_global_load_lds(
      (const __attribute__((address_space(1))) u32*)g,
      (__attribute__((address_space(3))) u32*)l, 16, 0, 0);
}

__device__ __forceinline__ f32x16 mfma16(uint4 a, uint4 b, f32x16 c) {
  return __builtin_amdgcn_mfma_f32_32x32x16_bf16(
      __builtin_bit_cast(bf16x8, a), __builtin_bit_cast(bf16x8, b), c, 0, 0, 0);
}

// ---------------------------------------------------------------------------
// Prep: f32 weights -> bf16 transposed. wst[s][u][d]:
//   s=0..4 -> spline_weight[d][u][s]; s=5 -> base_weight[d][u].
// grid (32,4): d-tiles of 32, u-tiles of 32; 256 threads.
// ---------------------------------------------------------------------------
__global__ __launch_bounds__(256) void kan_prep(const float* __restrict__ wb,
                                                const float* __restrict__ ws,
                                                u16* __restrict__ wst) {
  __shared__ __align__(16) u16 tile[6][32][40];  // 80 B rows: 16B-aligned, non-pow2
  const int t = threadIdx.x;
  const int d0 = blockIdx.x * 32;
  const int u0 = blockIdx.y * 32;
#pragma unroll
  for (int it = 0; it < 4; ++it) {
    int e = it * 256 + t;
    int uu = e & 31, dd = e >> 5;  // dd 0..31
    const float* p = ws + ((size_t)(d0 + dd) * 128 + (u0 + uu)) * 8;
    float4 v0 = *(const float4*)p;  // g=0..3
    float g4 = p[4];
    tile[0][uu][dd] = f2bf(v0.x);
    tile[1][uu][dd] = f2bf(v0.y);
    tile[2][uu][dd] = f2bf(v0.z);
    tile[3][uu][dd] = f2bf(v0.w);
    tile[4][uu][dd] = f2bf(g4);
    tile[5][uu][dd] = f2bf(wb[(size_t)(d0 + dd) * 128 + (u0 + uu)]);
  }
  __syncthreads();
#pragma unroll
  for (int it = 0; it < 3; ++it) {
    int v = it * 256 + t;  // 768 granules = 6 subs * 32 u * 4 d-segs
    int s = v >> 7;
    int r = v & 127;
    int uu = r >> 2, dseg = r & 3;
    uint4 val = *(const uint4*)&tile[s][uu][dseg * 8];
    *(uint4*)(wst + (size_t)(s * 128 + u0 + uu) * 1024 + d0 + dseg * 8) = val;
  }
}

// ---------------------------------------------------------------------------
// Main fused kernel. grid 256, block 512 (8 waves as 2m x 4n, wave 32x32).
// M=64, N=128, BK=32, double-buffered LDS (144 KB), one barrier per chunk.
// LDS swizzle (both As and Bs): two 64B rows form a 128B super-row; the 16B
// granule of (row r, seg s) sits at q = ((r&1)*4+s) ^ ((r>>1)&7)  -> uniform
// 4 lanes/granule for frag reads & rbf writes (conflict-free), and DMA slots
// stay linear (content permutation only).
// Layout per buffer (73728 B): As 6 subs x 64 rows x 64 B   at byte 0
//                              Bs 6 subs x 128 rows x 64 B  at byte 24576
// Subs 0..4 = rbf_g, 5 = bf16(x).
// mfma_f32_32x32x16_bf16: A[m=lane&31][k=(lane>>5)*8+j] (R2-validated),
// C/D: col=lane&31, row=(reg&3)+8*(reg>>2)+4*(lane>>5).
// ---------------------------------------------------------------------------
__global__ __launch_bounds__(512, 2) void kan_main(const float* __restrict__ x,
                                                   const u16* __restrict__ wst,
                                                   float* __restrict__ out) {
  __shared__ __align__(16) u16 lds[73728];  // 147456 B = 2 x 73728 B buffers
  char* ldsb = (char*)&lds[0];

  const int t = threadIdx.x;
  const int lane = t & 63;
  const int w = t >> 6;
  const int wm = w >> 2;  // 0..1
  const int wn = w & 3;   // 0..3
  const int b0 = blockIdx.x * 64;

  f32x16 accb, accs;
#pragma unroll
  for (int i = 0; i < 16; ++i) { accb[i] = 0.f; accs[i] = 0.f; }

  // ---- rbf writer indices: thread t -> row rr = t>>3, 8B-slot h = t&7
  const int rr = t >> 3, h = t & 7;
  const int rsr = rr >> 1;
  const u32 aw_off = (u32)(rsr * 128 +
                           (((((rr & 1) << 2) | (h >> 1)) ^ (rsr & 7)) << 4) +
                           ((h & 1) << 3));
  const float* xbase = x + (size_t)(b0 + rr) * 1024 + h * 4;

  // ---- DMA content mapping (inverse swizzle), invariant over subs/chunks
  const int dR = t >> 3, dq = t & 7;
  const int dv = dq ^ (dR & 7);
  const int durow = 2 * dR + (dv >> 2);
  const int dseg = dv & 3;
  const u16* dsrc0 = wst + ((size_t)durow << 10) + dseg * 8;  // + sub*131072 + k0

  // ---- MFMA fragment offsets (bytes within buffer), per kk
  const int ml = lane & 31, kh = lane >> 5;
  const int ar = wm * 32 + ml, asr = ar >> 1;
  const u32 aoff0 = (u32)(asr * 128 + (((((ar & 1) << 2) | kh) ^ (asr & 7)) << 4));
  const u32 aoff1 = (u32)(asr * 128 + (((((ar & 1) << 2) | (2 + kh)) ^ (asr & 7)) << 4));
  const int br = wn * 32 + ml, bsr = br >> 1;
  const u32 boff0 = (u32)(24576 + bsr * 128 + (((((br & 1) << 2) | kh) ^ (bsr & 7)) << 4));
  const u32 boff1 = (u32)(24576 + bsr * 128 + (((((br & 1) << 2) | (2 + kh)) ^ (bsr & 7)) << 4));

  // ===== helpers as lambdas ==================================================
  auto dma_weights = [&](int k0, char* buf) {
#pragma unroll
    for (int i = 0; i < 6; ++i) {
      async16(dsrc0 + ((size_t)i << 17) + k0, buf + 24576 + ((i * 512 + t) << 4));
    }
  };
  auto rbf_write = [&](char* buf, float4 xa) {
    float xf[4] = {xa.x, xa.y, xa.z, xa.w};
    float rv[6][4];
#pragma unroll
    for (int e = 0; e < 4; ++e) {
      float xv = xf[e];
      float t0 = C2 * xv;
      float P = __builtin_amdgcn_exp2f(t0 * xv);   // e^{-5x^2}
      float Qp = __builtin_amdgcn_exp2f(-t0);      // e^{+5x}
      float Qm = __builtin_amdgcn_exp2f(t0);       // e^{-5x}
      float PQ = P * Qp, PQm = P * Qm;
      rv[0][e] = PQm * Qm * T2C;  // c=-1
      rv[1][e] = PQm * T1C;       // c=-0.5
      rv[2][e] = P;               // c=0
      rv[3][e] = PQ * T1C;        // c=+0.5
      rv[4][e] = PQ * Qp * T2C;   // c=+1
      rv[5][e] = xv;              // base path
    }
#pragma unroll
    for (int s = 0; s < 6; ++s) {
      uint2 pk;
      pk.x = (u32)f2bf(rv[s][0]) | ((u32)f2bf(rv[s][1]) << 16);
      pk.y = (u32)f2bf(rv[s][2]) | ((u32)f2bf(rv[s][3]) << 16);
      *(uint2*)(buf + s * 4096 + aw_off) = pk;
    }
  };

  // ===== pipeline ============================================================
  float4 xreg = *(const float4*)(xbase);
  dma_weights(0, ldsb);
  rbf_write(ldsb, xreg);
  xreg = *(const float4*)(xbase + 32);
  __syncthreads();

  for (int k = 0; k < 32; ++k) {
    char* cb = ldsb + (size_t)(k & 1) * 73728;
    if (k < 31) {
      char* nb = ldsb + (size_t)((k + 1) & 1) * 73728;
      dma_weights((k + 1) * 32, nb);
      rbf_write(nb, xreg);
    }
    if (k < 30) xreg = *(const float4*)(xbase + (k + 2) * 32);

#pragma unroll
    for (int s = 0; s < 6; ++s) {
      uint4 a0 = *(const uint4*)(cb + s * 4096 + aoff0);
      uint4 b0v = *(const uint4*)(cb + s * 8192 + boff0);
      uint4 a1 = *(const uint4*)(cb + s * 4096 + aoff1);
      uint4 b1v = *(const uint4*)(cb + s * 8192 + boff1);
      if (s < 5) {
        accs = mfma16(a0, b0v, accs);
        accs = mfma16(a1, b1v, accs);
      } else {
        accb = mfma16(a0, b0v, accb);
        accb = mfma16(a1, b1v, accb);
      }
    }
    __syncthreads();
  }

  // ===== epilogue: silu(base) + spline, f32 stores ==========================
  const int n = wn * 32 + ml;
#pragma unroll
  for (int reg = 0; reg < 16; ++reg) {
    int row = (reg & 3) + 8 * (reg >> 2) + 4 * kh;
    int m = b0 + wm * 32 + row;
    float z = accb[reg];
    float sv = z / (1.0f + __expf(-z));
    out[(size_t)m * 128 + n] = sv + accs[reg];
  }
}

extern "C" void kernel_launch(void* const* d_in, const int* in_sizes, int n_in,
                              void* d_out, int out_size, void* d_ws, size_t ws_size,
                              hipStream_t stream) {
  const float* x  = (const float*)d_in[0];   // [16384][1024] f32
  const float* wb = (const float*)d_in[1];   // [1024][128]   f32
  const float* ws = (const float*)d_in[2];   // [1024][128][8] f32
  u16* wst = (u16*)d_ws;                     // [6][128][1024] bf16 = 1.5 MB
  float* out = (float*)d_out;                // [16384][128]  f32

  kan_prep<<<dim3(32, 4), 256, 0, stream>>>(wb, ws, wst);
  kan_main<<<dim3(256), 512, 0, stream>>>(x, wst, out);
}